// Round 5
// baseline (221.921 us; speedup 1.0000x reference)
//
#include <hip/hip_runtime.h>
#include <math.h>

#define BH 4
#define HH 512
#define WW 512
#define NPIX (BH * HH * WW)
#define CPB 32                 // columns per col-scan block
#define NXT (WW / CPB)         // 16 col tiles per image
#define NSEG 16                // row segments
#define SEGROWS 32             // rows per segment

// ws layout:
//   [0    .. 256)    : int blockAny[64]    (per col-scan block: any fg)
//   [256  .. 260)    : int ticket          (last-block election, zeroed by col_scan)
//   [512  .. 8704)   : float rowSum[2048]  (per row-loss block partial)
//   [16K  .. +4MB)   : float g2[NPIX]      (clamped squared 1D distances)

__global__ __launch_bounds__(512) void edt_col_scan(
    const int* __restrict__ tgt, float* __restrict__ g2,
    int* __restrict__ blockAny, int* __restrict__ ticket) {
    const int b   = blockIdx.x >> 4;
    const int xt  = blockIdx.x & 15;
    const int col = threadIdx.x & (CPB - 1);      // 0..31
    const int seg = threadIdx.x >> 5;             // 0..15
    const int x   = xt * CPB + col;
    const int y0  = seg * SEGROWS;
    const int* t  = tgt + b * HH * WW + x;
    float* gp     = g2  + b * HH * WW + x;

    if (blockIdx.x == 0 && threadIdx.x == 0) *ticket = 0;

    // load this thread's 32-row segment (independent loads, all in flight)
    int v[SEGROWS];
    #pragma unroll
    for (int i = 0; i < SEGROWS; ++i)
        v[i] = t[(y0 + i) * WW];

    // per-segment last/first foreground row (absolute); sentinels match ref
    int segLast = -1024, segFirst = 3 * 1024;
    #pragma unroll
    for (int i = 0; i < SEGROWS; ++i)
        if (v[i] > 0) segLast = y0 + i;
    #pragma unroll
    for (int i = SEGROWS - 1; i >= 0; --i)
        if (v[i] > 0) segFirst = y0 + i;

    __shared__ int sLast[NSEG][CPB];
    __shared__ int sFirst[NSEG][CPB];
    sLast[seg][col]  = segLast;
    sFirst[seg][col] = segFirst;
    __syncthreads();

    // carry-in from the other segments of this column
    int carryLast = -1024;
    #pragma unroll
    for (int s = 0; s < NSEG; ++s)
        if (s < seg) carryLast = max(carryLast, sLast[s][col]);
    int carryFirst = 3 * 1024;
    #pragma unroll
    for (int s = 0; s < NSEG; ++s)
        if (s > seg) carryFirst = min(carryFirst, sFirst[s][col]);

    // block-level has-foreground: seg-15 threads know the column's global last
    int fullLast = max(carryLast, segLast);
    unsigned long long bal = __ballot(seg == NSEG - 1 && fullLast >= 0);
    if (threadIdx.x == 512 - CPB) blockAny[blockIdx.x] = (bal != 0ull) ? 1 : 0;

    // forward: distance to last fg at-or-above
    int gup[SEGROWS];
    int last = carryLast;
    #pragma unroll
    for (int i = 0; i < SEGROWS; ++i) {
        int y = y0 + i;
        if (v[i] > 0) last = y;
        gup[i] = y - last;
    }
    // backward: combine with next fg at-or-below, clamp at big=1024, emit g^2
    int nxt = carryFirst;
    #pragma unroll
    for (int i = SEGROWS - 1; i >= 0; --i) {
        int y = y0 + i;
        if (v[i] > 0) nxt = y;
        int g = min(min(gup[i], nxt - y), 1024);
        float gf = (float)g;
        gp[y * WW] = gf * gf;
    }
}

__global__ __launch_bounds__(256) void edt_row_loss(
    const float* __restrict__ pred, const float* __restrict__ g2,
    float* __restrict__ rowSum, const int* __restrict__ blockAny,
    int* __restrict__ ticket, float* __restrict__ out) {
    const int row  = blockIdx.x;                  // b*HH + y
    const int base = row * WW;
    const int tid  = threadIdx.x;                 // 256

    // prefetch pred (overlaps the LDS fill + barrier)
    float pr0 = pred[base + tid];
    float pr1 = pred[base + tid + 256];

    __shared__ float sg2[WW];
    float2 gv = ((const float2*)(g2 + base))[tid];
    ((float2*)sg2)[tid] = gv;
    __syncthreads();

    float acc = 0.0f;
    #pragma unroll
    for (int k = 0; k < 2; ++k) {
        const int x = tid + k * 256;
        float m = sg2[x];                         // j == x candidate
        // exact expanding scan: once r^2 >= m, farther j cannot win (g2 >= 0)
        for (int r = 1; r < WW; ++r) {
            float r2 = (float)(r * r);
            if (r2 >= m) break;
            int jl = x - r, jr = x + r;
            if (jl >= 0) m = fminf(m, sg2[jl] + r2);
            if (jr < WW) m = fminf(m, sg2[jr] + r2);
            if (jl < 0 && jr >= WW) break;
        }
        float p = 1.0f / (1.0f + __expf(-(k == 0 ? pr0 : pr1)));
        acc += p * sqrtf(m);
    }

    #pragma unroll
    for (int off = 32; off > 0; off >>= 1)
        acc += __shfl_down(acc, off);
    __shared__ float sw[4];
    if ((tid & 63) == 0) sw[tid >> 6] = acc;
    __syncthreads();
    if (tid == 0) rowSum[row] = sw[0] + sw[1] + sw[2] + sw[3];

    // last-block reduction (rocPRIM pattern): release, ticket, acquire
    __threadfence();
    __shared__ int isLast;
    if (tid == 0) isLast = (atomicAdd(ticket, 1) == BH * HH - 1) ? 1 : 0;
    __syncthreads();
    if (isLast) {
        __threadfence();
        __shared__ float sflag[BH];
        if (tid < BH) {
            int a = 0;
            #pragma unroll
            for (int i = 0; i < NXT; ++i) a |= blockAny[tid * NXT + i];
            sflag[tid] = a ? 1.0f : 0.0f;
        }
        __syncthreads();
        float facc = 0.0f;
        for (int i = tid; i < BH * HH; i += 256)
            facc += rowSum[i] * sflag[i >> 9];
        #pragma unroll
        for (int off = 32; off > 0; off >>= 1)
            facc += __shfl_down(facc, off);
        __shared__ float fsw[4];
        if ((tid & 63) == 0) fsw[tid >> 6] = facc;
        __syncthreads();
        if (tid == 0)
            out[0] = (fsw[0] + fsw[1] + fsw[2] + fsw[3]) * (1.0f / (float)NPIX);
    }
}

extern "C" void kernel_launch(void* const* d_in, const int* in_sizes, int n_in,
                              void* d_out, int out_size, void* d_ws, size_t ws_size,
                              hipStream_t stream) {
    const float* pred = (const float*)d_in[0];
    const int* tgt    = (const int*)d_in[1];
    float* out        = (float*)d_out;

    char* ws      = (char*)d_ws;
    int* blockAny = (int*)ws;
    int* ticket   = (int*)(ws + 256);
    float* rowSum = (float*)(ws + 512);
    float* g2     = (float*)(ws + 16384);

    edt_col_scan<<<BH * NXT, 512, 0, stream>>>(tgt, g2, blockAny, ticket);
    edt_row_loss<<<BH * HH, 256, 0, stream>>>(pred, g2, rowSum, blockAny, ticket, out);
}

// Round 6
// 116.337 us; speedup vs baseline: 1.9076x; 1.9076x over previous
//
#include <hip/hip_runtime.h>
#include <math.h>

#define BH 4
#define HH 512
#define WW 512
#define NPIX (BH * HH * WW)
#define NTILES 8               // 512 cols / 64 lanes
#define NSEG 16                // 512 rows / 32
#define SEGROWS 32

// ws layout:
//   [0   .. 128)  : int blockAny[32]   (per col-scan block: any fg; plain writes)
//   [128 .. 132)  : int ticket         (zeroed by col_scan blk0)
//   [132 .. 136)  : float accum        (zeroed by col_scan blk0)
//   [16K .. +4MB) : float g2[NPIX]     (clamped squared 1D distances)

__global__ __launch_bounds__(1024) void edt_col_scan(
    const int* __restrict__ tgt, float* __restrict__ g2,
    int* __restrict__ blockAny, int* __restrict__ ticket,
    float* __restrict__ accum) {
    const int b    = blockIdx.x >> 3;
    const int xt   = blockIdx.x & 7;
    const int lane = threadIdx.x & 63;
    const int wave = threadIdx.x >> 6;            // 0..15
    const int x    = xt * 64 + lane;
    const int y0   = wave * SEGROWS;
    const int* t   = tgt + b * HH * WW + x;
    float* gp      = g2  + b * HH * WW + x;

    if (blockIdx.x == 0 && threadIdx.x == 0) { *ticket = 0; *accum = 0.0f; }

    // load this wave's 32-row segment (coalesced 256B per row, all in flight)
    int v[SEGROWS];
    #pragma unroll
    for (int i = 0; i < SEGROWS; ++i)
        v[i] = t[(y0 + i) * WW];

    // per-segment last/first foreground row (absolute), sentinels match ref
    int segLast = -1024, segFirst = 3 * 1024;
    #pragma unroll
    for (int i = 0; i < SEGROWS; ++i)
        if (v[i] > 0) segLast = y0 + i;
    #pragma unroll
    for (int i = SEGROWS - 1; i >= 0; --i)
        if (v[i] > 0) segFirst = y0 + i;

    __shared__ int sLast[NSEG][64];
    __shared__ int sFirst[NSEG][64];
    __shared__ int sAny[NSEG];
    sLast[wave][lane]  = segLast;
    sFirst[wave][lane] = segFirst;
    unsigned long long bal = __ballot(segLast >= 0);
    if (lane == 0) sAny[wave] = (bal != 0ull);
    __syncthreads();

    // carry-in from other segments of this column
    int carryLast = -1024;
    for (int s = 0; s < wave; ++s)
        carryLast = max(carryLast, sLast[s][lane]);
    int carryFirst = 3 * 1024;
    for (int s = wave + 1; s < NSEG; ++s)
        carryFirst = min(carryFirst, sFirst[s][lane]);

    // forward: distance to last fg at-or-above
    int gup[SEGROWS];
    int last = carryLast;
    #pragma unroll
    for (int i = 0; i < SEGROWS; ++i) {
        int y = y0 + i;
        if (v[i] > 0) last = y;
        gup[i] = y - last;
    }
    // backward: combine with distance to next fg at-or-below, clamp, emit g^2
    int nxt = carryFirst;
    #pragma unroll
    for (int i = SEGROWS - 1; i >= 0; --i) {
        int y = y0 + i;
        if (v[i] > 0) nxt = y;
        int g = min(min(gup[i], nxt - y), 1024);
        float gf = (float)g;
        gp[y * WW] = gf * gf;
    }

    if (threadIdx.x == 0) {
        int a = 0;
        #pragma unroll
        for (int s = 0; s < NSEG; ++s) a |= sAny[s];
        blockAny[blockIdx.x] = a;   // plain write; read by NEXT kernel (safe)
    }
}

__global__ __launch_bounds__(256) void edt_row_loss(
    const float* __restrict__ pred, const float* __restrict__ g2,
    const int* __restrict__ blockAny, int* __restrict__ ticket,
    float* __restrict__ accum, float* __restrict__ out) {
    const int row  = blockIdx.x;                  // b*HH + y
    const int b    = row >> 9;                    // HH == 512
    const int base = row * WW;
    const int tid  = threadIdx.x;                 // 256

    // prefetch pred (overlaps LDS fill + barrier)
    float pr0 = pred[base + tid];
    float pr1 = pred[base + tid + 256];

    __shared__ float sg2[WW];
    ((float2*)sg2)[tid] = ((const float2*)(g2 + base))[tid];
    __syncthreads();

    float acc = 0.0f;
    #pragma unroll
    for (int k = 0; k < 2; ++k) {
        const int x = tid + k * 256;
        float m = sg2[x];                         // j == x candidate
        // exact expanding scan: once r^2 >= m, farther j cannot win (g2 >= 0)
        for (int r = 1; r < WW; ++r) {
            float r2 = (float)(r * r);
            if (r2 >= m) break;
            int jl = x - r, jr = x + r;
            if (jl >= 0) m = fminf(m, sg2[jl] + r2);
            if (jr < WW) m = fminf(m, sg2[jr] + r2);
            if (jl < 0 && jr >= WW) break;
        }
        float p = 1.0f / (1.0f + __expf(-(k == 0 ? pr0 : pr1)));
        acc += p * sqrtf(m);
    }

    #pragma unroll
    for (int off = 32; off > 0; off >>= 1)
        acc += __shfl_down(acc, off);
    __shared__ float sw[4];
    if ((tid & 63) == 0) sw[tid >> 6] = acc;
    __syncthreads();

    if (tid == 0) {
        // has-foreground flag for this batch (written by previous kernel)
        int a = 0;
        #pragma unroll
        for (int i = 0; i < NTILES; ++i) a |= blockAny[b * NTILES + i];
        float val = (sw[0] + sw[1] + sw[2] + sw[3]) *
                    (a ? 1.0f : 0.0f) * (1.0f / (float)NPIX);

        // all-atomic completion protocol (no fences; atomics are device-coherent)
        float old = atomicAdd(accum, val);        // returns old -> forces vmcnt wait
        asm volatile("" :: "v"(old));             // consume: add committed before ticket
        int t = atomicAdd(ticket, 1);
        if (t == BH * HH - 1) {
            float total = atomicAdd(accum, 0.0f); // coherent atomic read of final sum
            out[0] = total;
        }
    }
}

extern "C" void kernel_launch(void* const* d_in, const int* in_sizes, int n_in,
                              void* d_out, int out_size, void* d_ws, size_t ws_size,
                              hipStream_t stream) {
    const float* pred = (const float*)d_in[0];
    const int* tgt    = (const int*)d_in[1];
    float* out        = (float*)d_out;

    char* ws      = (char*)d_ws;
    int* blockAny = (int*)ws;
    int* ticket   = (int*)(ws + 128);
    float* accum  = (float*)(ws + 132);
    float* g2     = (float*)(ws + 16384);

    edt_col_scan<<<BH * NTILES, 1024, 0, stream>>>(tgt, g2, blockAny, ticket, accum);
    edt_row_loss<<<BH * HH, 256, 0, stream>>>(pred, g2, blockAny, ticket, accum, out);
}

// Round 7
// 78.178 us; speedup vs baseline: 2.8387x; 1.4881x over previous
//
#include <hip/hip_runtime.h>
#include <math.h>

#define BH 4
#define HH 512
#define WW 512
#define NPIX (BH * HH * WW)
#define CPB 16                 // columns per col-scan block
#define NXT (WW / CPB)         // 32 col tiles per image
#define NSEG 16                // row segments
#define SEGROWS 32             // rows per segment
#define RPB 8                  // rows per row-loss block
#define NRB (BH * HH / RPB)    // 256 row-loss blocks
#define NSLOT 16

// ws layout:
//   [0    .. 512)   : int blockAny[128]   (per col-scan block: any fg)
//   [512  .. 516)   : int ticket          (zeroed by col_scan blk0)
//   [1024 .. 2048)  : float slots[16] @ 64B stride (zeroed by col_scan blk0)
//   [16K  .. +4MB)  : float g2[NPIX]      (clamped squared 1D distances)

__global__ __launch_bounds__(256) void edt_col_scan(
    const int* __restrict__ tgt, float* __restrict__ g2,
    int* __restrict__ blockAny, int* __restrict__ ticket,
    float* __restrict__ slots) {
    const int b   = blockIdx.x >> 5;
    const int xt  = blockIdx.x & 31;
    const int tid = threadIdx.x;
    const int col = tid & (CPB - 1);              // 0..15
    const int seg = tid >> 4;                     // 0..15
    const int x   = xt * CPB + col;
    const int y0  = seg * SEGROWS;
    const int* t  = tgt + b * HH * WW + x;
    float* gp     = g2  + b * HH * WW + x;

    if (blockIdx.x == 0) {
        if (tid == 0) *ticket = 0;
        if (tid < NSLOT) slots[tid * 16] = 0.0f;
    }

    // load this thread's 32-row segment (independent loads, all in flight)
    int v[SEGROWS];
    #pragma unroll
    for (int i = 0; i < SEGROWS; ++i)
        v[i] = t[(y0 + i) * WW];

    // per-segment last/first foreground row (absolute); sentinels match ref
    int segLast = -1024, segFirst = 3 * 1024;
    #pragma unroll
    for (int i = 0; i < SEGROWS; ++i)
        if (v[i] > 0) segLast = y0 + i;
    #pragma unroll
    for (int i = SEGROWS - 1; i >= 0; --i)
        if (v[i] > 0) segFirst = y0 + i;

    __shared__ int sLast[NSEG][CPB];
    __shared__ int sFirst[NSEG][CPB];
    __shared__ int sAnyW[4];
    sLast[seg][col]  = segLast;
    sFirst[seg][col] = segFirst;
    unsigned long long bal = __ballot(segLast >= 0);
    if ((tid & 63) == 0) sAnyW[tid >> 6] = (bal != 0ull);
    __syncthreads();

    // carry-in from the other segments of this column
    int carryLast = -1024;
    #pragma unroll
    for (int s = 0; s < NSEG; ++s)
        if (s < seg) carryLast = max(carryLast, sLast[s][col]);
    int carryFirst = 3 * 1024;
    #pragma unroll
    for (int s = 0; s < NSEG; ++s)
        if (s > seg) carryFirst = min(carryFirst, sFirst[s][col]);

    // forward: distance to last fg at-or-above
    int gup[SEGROWS];
    int last = carryLast;
    #pragma unroll
    for (int i = 0; i < SEGROWS; ++i) {
        int y = y0 + i;
        if (v[i] > 0) last = y;
        gup[i] = y - last;
    }
    // backward: combine with next fg at-or-below, clamp at big=1024, emit g^2
    int nxt = carryFirst;
    #pragma unroll
    for (int i = SEGROWS - 1; i >= 0; --i) {
        int y = y0 + i;
        if (v[i] > 0) nxt = y;
        int g = min(min(gup[i], nxt - y), 1024);
        float gf = (float)g;
        gp[y * WW] = gf * gf;
    }

    if (tid == 0)
        blockAny[blockIdx.x] = sAnyW[0] | sAnyW[1] | sAnyW[2] | sAnyW[3];
}

__global__ __launch_bounds__(256) void edt_row_loss(
    const float* __restrict__ pred, const float* __restrict__ g2,
    const int* __restrict__ blockAny, int* __restrict__ ticket,
    float* __restrict__ slots, float* __restrict__ out) {
    const int rb   = blockIdx.x;                  // covers rows [rb*8, rb*8+8)
    const int b    = rb >> 6;                     // 64 blocks per image
    const int base = rb * RPB * WW;
    const int tid  = threadIdx.x;                 // 256

    // has-foreground for this batch (from previous kernel; wave0 ballot)
    unsigned long long abal =
        __ballot(tid < NXT && blockAny[b * NXT + tid] != 0);

    // prefetch this thread's 16 pred values (cols tid, tid+256 of 8 rows)
    float pr[RPB][2];
    #pragma unroll
    for (int i = 0; i < RPB; ++i) {
        pr[i][0] = pred[base + i * WW + tid];
        pr[i][1] = pred[base + i * WW + tid + 256];
    }

    __shared__ float sg2[RPB * WW];               // 16 KB
    {
        const float2* src = (const float2*)(g2 + base);
        float2* dst = (float2*)sg2;
        #pragma unroll
        for (int i = 0; i < RPB; ++i)
            dst[tid + i * 256] = src[tid + i * 256];
    }
    __syncthreads();

    float acc = 0.0f;
    #pragma unroll
    for (int i = 0; i < RPB; ++i) {
        const float* srow = sg2 + i * WW;
        #pragma unroll
        for (int k = 0; k < 2; ++k) {
            const int x = tid + k * 256;
            float m = srow[x];                    // j == x candidate
            // exact expanding scan: once r^2 >= m, farther j cannot win
            for (int r = 1; r < WW; ++r) {
                float r2 = (float)(r * r);
                if (r2 >= m) break;
                int jl = x - r, jr = x + r;
                if (jl >= 0) m = fminf(m, srow[jl] + r2);
                if (jr < WW) m = fminf(m, srow[jr] + r2);
                if (jl < 0 && jr >= WW) break;
            }
            float p = 1.0f / (1.0f + __expf(-pr[i][k]));
            acc += p * sqrtf(m);
        }
    }

    #pragma unroll
    for (int off = 32; off > 0; off >>= 1)
        acc += __shfl_down(acc, off);
    __shared__ float sw[4];
    if ((tid & 63) == 0) sw[tid >> 6] = acc;
    __syncthreads();

    if (tid == 0) {
        float fscale = (abal != 0ull) ? (1.0f / (float)NPIX) : 0.0f;
        float val = (sw[0] + sw[1] + sw[2] + sw[3]) * fscale;

        // spread-slot accumulate (16 cache lines), then single ticket line
        float old = atomicAdd(&slots[(rb & (NSLOT - 1)) * 16], val);
        asm volatile("" :: "v"(old));             // add committed before ticket
        int t = atomicAdd(ticket, 1);
        if (t == NRB - 1) {
            float total = 0.0f;
            #pragma unroll
            for (int i = 0; i < NSLOT; ++i)
                total += atomicAdd(&slots[i * 16], 0.0f);  // coherent reads
            out[0] = total;
        }
    }
}

extern "C" void kernel_launch(void* const* d_in, const int* in_sizes, int n_in,
                              void* d_out, int out_size, void* d_ws, size_t ws_size,
                              hipStream_t stream) {
    const float* pred = (const float*)d_in[0];
    const int* tgt    = (const int*)d_in[1];
    float* out        = (float*)d_out;

    char* ws      = (char*)d_ws;
    int* blockAny = (int*)ws;
    int* ticket   = (int*)(ws + 512);
    float* slots  = (float*)(ws + 1024);
    float* g2     = (float*)(ws + 16384);

    edt_col_scan<<<BH * NXT, 256, 0, stream>>>(tgt, g2, blockAny, ticket, slots);
    edt_row_loss<<<NRB, 256, 0, stream>>>(pred, g2, blockAny, ticket, slots, out);
}

// Round 8
// 77.205 us; speedup vs baseline: 2.8744x; 1.0126x over previous
//
#include <hip/hip_runtime.h>
#include <math.h>

#define BH 4
#define HH 512
#define WW 512
#define NPIX (BH * HH * WW)
#define NTILES 8               // 512 cols / 64 lanes (col_scan blocks per image)
#define NSEG 16                // 512 rows / 32
#define SEGROWS 32
#define NSLOT 16               // partial-sum slots, 64B apart
#define NSUB 8                 // arrival sub-tickets, 64B apart

// ws layout (all control words < 16K, zero-inited by col_scan block 0):
//   [0    .. 128)  : int blockAny[32]      (per col-scan block: any fg)
//   [256  .. 768)  : int sub[8]   @64B     (arrival sub-tickets)
//   [1024 .. 1028) : int final             (finisher ticket)
//   [2048 .. 3072) : float slots[16] @64B  (spread partial sums)
//   [16K  .. +4MB) : float g2[NPIX]        (clamped squared 1D distances)

__global__ __launch_bounds__(1024) void edt_col_scan(
    const int* __restrict__ tgt, float* __restrict__ g2,
    int* __restrict__ blockAny, int* __restrict__ sub,
    int* __restrict__ finalT, float* __restrict__ slots) {
    const int b    = blockIdx.x >> 3;
    const int xt   = blockIdx.x & 7;
    const int lane = threadIdx.x & 63;
    const int wave = threadIdx.x >> 6;            // 0..15
    const int x    = xt * 64 + lane;
    const int y0   = wave * SEGROWS;
    const int* t   = tgt + b * HH * WW + x;
    float* gp      = g2  + b * HH * WW + x;

    if (blockIdx.x == 0) {                        // zero control words
        const int tid = threadIdx.x;
        if (tid < NSUB) sub[tid * 16] = 0;
        if (tid == NSUB) *finalT = 0;
        if (tid >= 16 && tid < 16 + NSLOT) slots[(tid - 16) * 16] = 0.0f;
    }

    // load this wave's 32-row segment (coalesced 256B per row, all in flight)
    int v[SEGROWS];
    #pragma unroll
    for (int i = 0; i < SEGROWS; ++i)
        v[i] = t[(y0 + i) * WW];

    // per-segment last/first foreground row (absolute), sentinels match ref
    int segLast = -1024, segFirst = 3 * 1024;
    #pragma unroll
    for (int i = 0; i < SEGROWS; ++i)
        if (v[i] > 0) segLast = y0 + i;
    #pragma unroll
    for (int i = SEGROWS - 1; i >= 0; --i)
        if (v[i] > 0) segFirst = y0 + i;

    __shared__ int sLast[NSEG][64];
    __shared__ int sFirst[NSEG][64];
    __shared__ int sAny[NSEG];
    sLast[wave][lane]  = segLast;
    sFirst[wave][lane] = segFirst;
    unsigned long long bal = __ballot(segLast >= 0);
    if (lane == 0) sAny[wave] = (bal != 0ull);
    __syncthreads();

    // carry-in from other segments of this column
    int carryLast = -1024;
    for (int s = 0; s < wave; ++s)
        carryLast = max(carryLast, sLast[s][lane]);
    int carryFirst = 3 * 1024;
    for (int s = wave + 1; s < NSEG; ++s)
        carryFirst = min(carryFirst, sFirst[s][lane]);

    // forward: distance to last fg at-or-above
    int gup[SEGROWS];
    int last = carryLast;
    #pragma unroll
    for (int i = 0; i < SEGROWS; ++i) {
        int y = y0 + i;
        if (v[i] > 0) last = y;
        gup[i] = y - last;
    }
    // backward: combine with distance to next fg at-or-below, clamp, emit g^2
    int nxt = carryFirst;
    #pragma unroll
    for (int i = SEGROWS - 1; i >= 0; --i) {
        int y = y0 + i;
        if (v[i] > 0) nxt = y;
        int g = min(min(gup[i], nxt - y), 1024);
        float gf = (float)g;
        gp[y * WW] = gf * gf;
    }

    if (threadIdx.x == 0) {
        int a = 0;
        #pragma unroll
        for (int s = 0; s < NSEG; ++s) a |= sAny[s];
        blockAny[blockIdx.x] = a;   // plain write; read by NEXT kernel (safe)
    }
}

__global__ __launch_bounds__(256) void edt_row_loss(
    const float* __restrict__ pred, const float* __restrict__ g2,
    const int* __restrict__ blockAny, int* __restrict__ sub,
    int* __restrict__ finalT, float* __restrict__ slots,
    float* __restrict__ out) {
    const int row  = blockIdx.x;                  // b*HH + y   (2048 blocks)
    const int b    = row >> 9;                    // HH == 512
    const int base = row * WW;
    const int tid  = threadIdx.x;                 // 256

    // prefetch pred (overlaps LDS fill + barrier)
    float pr0 = pred[base + tid];
    float pr1 = pred[base + tid + 256];

    __shared__ float sg2[WW];
    ((float2*)sg2)[tid] = ((const float2*)(g2 + base))[tid];
    __syncthreads();

    float acc = 0.0f;
    #pragma unroll
    for (int k = 0; k < 2; ++k) {
        const int x = tid + k * 256;
        float m = sg2[x];                         // j == x candidate
        // exact expanding scan: once r^2 >= m, farther j cannot win (g2 >= 0)
        for (int r = 1; r < WW; ++r) {
            float r2 = (float)(r * r);
            if (r2 >= m) break;
            int jl = x - r, jr = x + r;
            if (jl >= 0) m = fminf(m, sg2[jl] + r2);
            if (jr < WW) m = fminf(m, sg2[jr] + r2);
            if (jl < 0 && jr >= WW) break;
        }
        float p = 1.0f / (1.0f + __expf(-(k == 0 ? pr0 : pr1)));
        acc += p * sqrtf(m);
    }

    #pragma unroll
    for (int off = 32; off > 0; off >>= 1)
        acc += __shfl_down(acc, off);
    __shared__ float sw[4];
    if ((tid & 63) == 0) sw[tid >> 6] = acc;
    __syncthreads();

    if (tid == 0) {
        int a = 0;
        #pragma unroll
        for (int i = 0; i < NTILES; ++i) a |= blockAny[b * NTILES + i];
        float val = (sw[0] + sw[1] + sw[2] + sw[3]) *
                    (a ? 1.0f : 0.0f) * (1.0f / (float)NPIX);

        // spread-line accumulate + hierarchical arrival (all relaxed atomics,
        // ordering by consuming each returned value before the next RMW)
        float old = atomicAdd(&slots[(row & (NSLOT - 1)) * 16], val);
        asm volatile("" :: "v"(old));             // slot add committed first
        int s = atomicAdd(&sub[(row & (NSUB - 1)) * 16], 1);
        if (s == (BH * HH / NSUB) - 1) {          // last block of this subgroup
            int f = atomicAdd(finalT, 1);
            if (f == NSUB - 1) {                  // last subgroup overall
                float total = 0.0f;
                #pragma unroll
                for (int i = 0; i < NSLOT; ++i)
                    total += atomicAdd(&slots[i * 16], 0.0f);  // coherent reads
                out[0] = total;
            }
        }
    }
}

extern "C" void kernel_launch(void* const* d_in, const int* in_sizes, int n_in,
                              void* d_out, int out_size, void* d_ws, size_t ws_size,
                              hipStream_t stream) {
    const float* pred = (const float*)d_in[0];
    const int* tgt    = (const int*)d_in[1];
    float* out        = (float*)d_out;

    char* ws      = (char*)d_ws;
    int* blockAny = (int*)ws;
    int* sub      = (int*)(ws + 256);
    int* finalT   = (int*)(ws + 1024);
    float* slots  = (float*)(ws + 2048);
    float* g2     = (float*)(ws + 16384);

    edt_col_scan<<<BH * NTILES, 1024, 0, stream>>>(tgt, g2, blockAny, sub, finalT, slots);
    edt_row_loss<<<BH * HH, 256, 0, stream>>>(pred, g2, blockAny, sub, finalT, slots, out);
}

// Round 9
// 71.843 us; speedup vs baseline: 3.0890x; 1.0746x over previous
//
#include <hip/hip_runtime.h>
#include <math.h>

#define BH 4
#define HH 512
#define WW 512
#define NPIX (BH * HH * WW)
#define CPB 16                 // columns per col-scan block
#define NXT (WW / CPB)         // 32 col tiles per image -> 128 blocks
#define NSEG 64                // row segments per column
#define SEGROWS 8              // rows per segment

// ws layout (no atomics, no control words):
//   [0   .. 512)   : int blockAny[128]   (per col-scan block: any fg)
//   [512 .. 8704)  : float rowSum[2048]  (per-row partial sums)
//   [16K .. +4MB)  : float g2[NPIX]      (clamped squared 1D distances)

__global__ __launch_bounds__(1024) void edt_col_scan(
    const int* __restrict__ tgt, float* __restrict__ g2,
    int* __restrict__ blockAny) {
    const int b   = blockIdx.x >> 5;
    const int xt  = blockIdx.x & 31;
    const int tid = threadIdx.x;
    const int col = tid & (CPB - 1);              // 0..15
    const int seg = tid >> 4;                     // 0..63
    const int x   = xt * CPB + col;
    const int y0  = seg * SEGROWS;
    const int* t  = tgt + b * HH * WW + x;
    float* gp     = g2  + b * HH * WW + x;

    // load this thread's 8-row segment (independent loads, all in flight)
    int v[SEGROWS];
    #pragma unroll
    for (int i = 0; i < SEGROWS; ++i)
        v[i] = t[(y0 + i) * WW];

    // per-segment last/first foreground row (absolute); sentinels match ref
    int segLast = -1024, segFirst = 3 * 1024;
    #pragma unroll
    for (int i = 0; i < SEGROWS; ++i)
        if (v[i] > 0) segLast = y0 + i;
    #pragma unroll
    for (int i = SEGROWS - 1; i >= 0; --i)
        if (v[i] > 0) segFirst = y0 + i;

    __shared__ int sLast[NSEG][CPB];
    __shared__ int sFirst[NSEG][CPB];
    __shared__ int sAny[16];
    sLast[seg][col]  = segLast;
    sFirst[seg][col] = segFirst;
    unsigned long long bal = __ballot(segLast >= 0);
    if ((tid & 63) == 0) sAny[tid >> 6] = (bal != 0ull);
    __syncthreads();

    // carry-in from the other segments of this column
    // (reads are 4-lane broadcasts of 16 banks -> conflict-free)
    int carryLast = -1024;
    #pragma unroll
    for (int s = 0; s < NSEG; ++s)
        if (s < seg) carryLast = max(carryLast, sLast[s][col]);
    int carryFirst = 3 * 1024;
    #pragma unroll
    for (int s = 0; s < NSEG; ++s)
        if (s > seg) carryFirst = min(carryFirst, sFirst[s][col]);

    // forward: distance to last fg at-or-above
    int gup[SEGROWS];
    int last = carryLast;
    #pragma unroll
    for (int i = 0; i < SEGROWS; ++i) {
        int y = y0 + i;
        if (v[i] > 0) last = y;
        gup[i] = y - last;
    }
    // backward: combine with next fg at-or-below, clamp at big=1024, emit g^2
    int nxt = carryFirst;
    #pragma unroll
    for (int i = SEGROWS - 1; i >= 0; --i) {
        int y = y0 + i;
        if (v[i] > 0) nxt = y;
        int g = min(min(gup[i], nxt - y), 1024);
        float gf = (float)g;
        gp[y * WW] = gf * gf;                     // 16 cols * 4B = 64B/row
    }

    if (tid == 0) {
        int a = 0;
        #pragma unroll
        for (int s = 0; s < 16; ++s) a |= sAny[s];
        blockAny[blockIdx.x] = a;                 // plain write; next kernel reads
    }
}

__global__ __launch_bounds__(256) void edt_row_loss(
    const float* __restrict__ pred, const float* __restrict__ g2,
    float* __restrict__ rowSum) {
    const int row  = blockIdx.x;                  // b*HH + y   (2048 blocks)
    const int base = row * WW;
    const int tid  = threadIdx.x;                 // 256

    // prefetch pred (overlaps LDS fill + barrier)
    float pr0 = pred[base + tid];
    float pr1 = pred[base + tid + 256];

    __shared__ float sg2[WW];
    ((float2*)sg2)[tid] = ((const float2*)(g2 + base))[tid];
    __syncthreads();

    float acc = 0.0f;
    #pragma unroll
    for (int k = 0; k < 2; ++k) {
        const int x = tid + k * 256;
        float m = sg2[x];                         // j == x candidate
        // exact expanding scan: once r^2 >= m, farther j cannot win (g2 >= 0)
        for (int r = 1; r < WW; ++r) {
            float r2 = (float)(r * r);
            if (r2 >= m) break;
            int jl = x - r, jr = x + r;
            if (jl >= 0) m = fminf(m, sg2[jl] + r2);
            if (jr < WW) m = fminf(m, sg2[jr] + r2);
            if (jl < 0 && jr >= WW) break;
        }
        float p = 1.0f / (1.0f + __expf(-(k == 0 ? pr0 : pr1)));
        acc += p * sqrtf(m);
    }

    #pragma unroll
    for (int off = 32; off > 0; off >>= 1)
        acc += __shfl_down(acc, off);
    __shared__ float sw[4];
    if ((tid & 63) == 0) sw[tid >> 6] = acc;
    __syncthreads();
    if (tid == 0) rowSum[row] = sw[0] + sw[1] + sw[2] + sw[3];
}

__global__ __launch_bounds__(1024) void finalize(
    const float* __restrict__ rowSum, const int* __restrict__ blockAny,
    float* __restrict__ out) {
    const int tid = threadIdx.x;                  // 1024

    __shared__ int sflagI[BH];
    if (tid < BH) sflagI[tid] = 0;
    __syncthreads();
    if (tid < BH * NXT) {                         // 128 loads, all in flight
        int a = blockAny[tid];
        if (a) atomicOr(&sflagI[tid >> 5], 1);    // LDS atomic (cheap)
    }
    __syncthreads();

    float acc = rowSum[tid]        * (sflagI[tid >> 9] ? 1.0f : 0.0f);
    acc      += rowSum[tid + 1024] * (sflagI[(tid + 1024) >> 9] ? 1.0f : 0.0f);

    #pragma unroll
    for (int off = 32; off > 0; off >>= 1)
        acc += __shfl_down(acc, off);
    __shared__ float sw[16];
    if ((tid & 63) == 0) sw[tid >> 6] = acc;
    __syncthreads();
    if (tid == 0) {
        float total = 0.0f;
        #pragma unroll
        for (int i = 0; i < 16; ++i) total += sw[i];
        out[0] = total * (1.0f / (float)NPIX);
    }
}

extern "C" void kernel_launch(void* const* d_in, const int* in_sizes, int n_in,
                              void* d_out, int out_size, void* d_ws, size_t ws_size,
                              hipStream_t stream) {
    const float* pred = (const float*)d_in[0];
    const int* tgt    = (const int*)d_in[1];
    float* out        = (float*)d_out;

    char* ws      = (char*)d_ws;
    int* blockAny = (int*)ws;
    float* rowSum = (float*)(ws + 512);
    float* g2     = (float*)(ws + 16384);

    edt_col_scan<<<BH * NXT, 1024, 0, stream>>>(tgt, g2, blockAny);
    edt_row_loss<<<BH * HH, 256, 0, stream>>>(pred, g2, rowSum);
    finalize<<<1, 1024, 0, stream>>>(rowSum, blockAny, out);
}